// Round 6
// baseline (211.093 us; speedup 1.0000x reference)
//
#include <hip/hip_runtime.h>
#include <math.h>

typedef float f2 __attribute__((ext_vector_type(2)));
typedef float f2u __attribute__((ext_vector_type(2), aligned(4)));
typedef float f4 __attribute__((ext_vector_type(4)));

#define BN 8
#define CIN 3
#define HH 512
#define WW 512
#define KK 9
#define PATCH 27
#define TAPBLK 96  // 56 (wy,wx) pair floats | 28 wm | 12 contraction = 96

// ws layout, tap k block of 96 floats (identical to proven baseline):
//  r in [0,56):  pair q=r>>1, half=r&1 -> w_off[(2k+half)*27+q], q>=27 -> 0
//  r in [56,84): i=r-56 -> w_off[(18+k)*27+i], i>=27 -> 0
//  r in [84,96): j=r-84, c=j>>2, o=j&3 -> o<3 ? w_def[o*27 + c*9 + k] : 0
__global__ void reorder_weights(const float* __restrict__ w_off,
                                const float* __restrict__ w_def,
                                float* __restrict__ ws)
{
    for (int idx = threadIdx.x; idx < KK * TAPBLK; idx += blockDim.x) {
        const int k = idx / TAPBLK;
        const int r = idx % TAPBLK;
        float v = 0.0f;
        if (r < 56) {
            const int q = r >> 1, half = r & 1;
            if (q < PATCH) v = w_off[(2 * k + half) * PATCH + q];
        } else if (r < 84) {
            const int i = r - 56;
            if (i < PATCH) v = w_off[(18 + k) * PATCH + i];
        } else {
            const int j = r - 84;
            const int c = j >> 2, o = j & 3;
            if (o < 3) v = w_def[o * PATCH + c * KK + k];
        }
        ws[idx] = v;
    }
}

// patch accessor: flat elem J = c*9 + rr*3 + cc; P = pixel (0=A, 1=B).
// J==27 is the pad element -> literal 0 (folds in unrolled code).
#define PAT(J, P) ((J) >= PATCH ? 0.0f : pr[((J) / 9) * 3 + (((J) % 9) / 3)][((J) % 3) + (P)])

// per-tap 27->3ch conv for BOTH pixels; writes oyxA/omA/oyxB/omB in enclosing scope
#define CONV_TAP(K) do {                                                \
    const float* blk_ = wsw + (K) * TAPBLK;                             \
    f2 aA_ = { b_off[2 * (K)], b_off[2 * (K) + 1] };                    \
    f2 aB_ = aA_;                                                       \
    float sA_ = b_off[18 + (K)];                                        \
    float sB_ = sA_;                                                    \
    _Pragma("unroll")                                                   \
    for (int j = 0; j < 14; ++j) {                                      \
        const f4 wq_ = *(const f4*)(blk_ + 4 * j);                      \
        const f2 wv0_ = { wq_.x, wq_.y };                               \
        const f2 wv1_ = { wq_.z, wq_.w };                               \
        const f2 pA0_ = { PAT(2 * j, 0),     PAT(2 * j, 0) };           \
        const f2 pB0_ = { PAT(2 * j, 1),     PAT(2 * j, 1) };           \
        const f2 pA1_ = { PAT(2 * j + 1, 0), PAT(2 * j + 1, 0) };       \
        const f2 pB1_ = { PAT(2 * j + 1, 1), PAT(2 * j + 1, 1) };       \
        aA_ = __builtin_elementwise_fma(wv0_, pA0_, aA_);               \
        aB_ = __builtin_elementwise_fma(wv0_, pB0_, aB_);               \
        aA_ = __builtin_elementwise_fma(wv1_, pA1_, aA_);               \
        aB_ = __builtin_elementwise_fma(wv1_, pB1_, aB_);               \
    }                                                                   \
    _Pragma("unroll")                                                   \
    for (int j = 0; j < 7; ++j) {                                       \
        const f4 wm_ = *(const f4*)(blk_ + 56 + 4 * j);                 \
        sA_ = fmaf(wm_.x, PAT(4 * j, 0),     sA_);                      \
        sB_ = fmaf(wm_.x, PAT(4 * j, 1),     sB_);                      \
        sA_ = fmaf(wm_.y, PAT(4 * j + 1, 0), sA_);                      \
        sB_ = fmaf(wm_.y, PAT(4 * j + 1, 1), sB_);                      \
        sA_ = fmaf(wm_.z, PAT(4 * j + 2, 0), sA_);                      \
        sB_ = fmaf(wm_.z, PAT(4 * j + 2, 1), sB_);                      \
        sA_ = fmaf(wm_.w, PAT(4 * j + 3, 0), sA_);                      \
        sB_ = fmaf(wm_.w, PAT(4 * j + 3, 1), sB_);                      \
    }                                                                   \
    oyxA = aA_; omA = sA_; oyxB = aB_; omB = sB_;                       \
} while (0)

__global__ __launch_bounds__(256) void deform_fused_kernel(
    const float* __restrict__ x,
    const float* __restrict__ wsw,    // reordered weights, 864 floats (uniform -> SMEM)
    const float* __restrict__ b_off,
    const float* __restrict__ b_def,
    float* __restrict__ out)
{
    const int t = threadIdx.x;        // 0..255
    const int w0 = 2 * t;             // pixel A; pixel B = w0+1
    const int h = blockIdx.y;
    const int b = blockIdx.z;

    const size_t plane = (size_t)HH * WW;
    const float* xb = x + (size_t)b * CIN * plane;

    // ---- shared 3x3x4 zero-padded patch: pr[c*3+row][col], cols w0-1..w0+2 ----
    float pr[9][4];
    #pragma unroll
    for (int c = 0; c < CIN; ++c) {
        const float* xp = xb + c * plane;
        #pragma unroll
        for (int r = 0; r < 3; ++r) {
            const int yy = h + r - 1;
            if (yy >= 0 && yy < HH) {                 // block-uniform branch
                const float* rowp = xp + yy * WW;
                const f2 mid = *(const f2u*)(rowp + w0);   // cols w0, w0+1 always valid
                pr[c * 3 + r][1] = mid.x;
                pr[c * 3 + r][2] = mid.y;
                pr[c * 3 + r][0] = (t > 0)   ? rowp[w0 - 1] : 0.0f;
                pr[c * 3 + r][3] = (t < 255) ? rowp[w0 + 2] : 0.0f;
            } else {
                pr[c * 3 + r][0] = 0.0f;
                pr[c * 3 + r][1] = 0.0f;
                pr[c * 3 + r][2] = 0.0f;
                pr[c * 3 + r][3] = 0.0f;
            }
        }
    }

    const float hf = (float)h;
    const float wfA = (float)w0;
    const float wfB = (float)(w0 + 1);

    f2 accA01 = { b_def[0], b_def[1] };
    float accA2 = b_def[2];
    f2 accB01 = accA01;
    float accB2 = accA2;

    // ---- prologue: conv for tap 0, both pixels ----
    f2 oyxA, oyxB;
    float omA, omB;
    CONV_TAP(0);

    // ---- software-pipelined tap loop ----
    // iter k: (A) issue gathers for tap k-1 (both px)  (B) conv tap k  (C) consume k-1
    #pragma unroll 1
    for (int k = 1; k <= KK; ++k) {
        const int kp = k - 1;
        const float* blkp = wsw + kp * TAPBLK;

        // -- phase A: contraction weights (uniform) + sampling setup + gathers --
        const f4 cw0 = *(const f4*)(blkp + 84);
        const f4 cw1 = *(const f4*)(blkp + 88);
        const f4 cw2 = *(const f4*)(blkp + 92);

        const float mA = 1.0f / (1.0f + __expf(-omA));
        const float mB = 1.0f / (1.0f + __expf(-omB));

        const float dyk = (float)(kp / 3 - 1);
        const float dxk = (float)(kp % 3 - 1);

        const float pyA = hf + dyk + oyxA.x;
        const float pxA = wfA + dxk + oyxA.y;
        const float pyB = hf + dyk + oyxB.x;
        const float pxB = wfB + dxk + oyxB.y;

        const float y0fA = floorf(pyA), x0fA = floorf(pxA);
        const float y0fB = floorf(pyB), x0fB = floorf(pxB);
        const float dyA = pyA - y0fA, dxA = pxA - x0fA;
        const float dyB = pyB - y0fB, dxB = pxB - x0fB;
        const int y0A = (int)y0fA, x0A = (int)x0fA;
        const int y0B = (int)y0fB, x0B = (int)x0fB;

        const f2 dxpA = { 1.0f - dxA, dxA };
        const f2 wTA = dxpA * (1.0f - dyA);
        const f2 wBA = dxpA * dyA;
        const f2 dxpB = { 1.0f - dxB, dxB };
        const f2 wTB = dxpB * (1.0f - dyB);
        const f2 wBB = dxpB * dyB;

        const int intA = (y0A >= 0) & (y0A + 1 < HH) & (x0A >= 0) & (x0A + 1 < WW);
        const int intB = (y0B >= 0) & (y0B + 1 < HH) & (x0B >= 0) & (x0B + 1 < WW);

        f2 vT0A, vB0A, vT1A, vB1A, vT2A, vB2A;
        f2 vT0B, vB0B, vT1B, vB1B, vT2B, vB2B;

        if (__all(intA & intB)) {
            const int idxA = y0A * WW + x0A;
            const int idxB = y0B * WW + x0B;
            const float* p0A = xb + idxA;
            const float* p0B = xb + idxB;
            vT0A = *(const f2u*)(p0A);           vB0A = *(const f2u*)(p0A + WW);
            vT0B = *(const f2u*)(p0B);           vB0B = *(const f2u*)(p0B + WW);
            vT1A = *(const f2u*)(p0A + plane);   vB1A = *(const f2u*)(p0A + plane + WW);
            vT1B = *(const f2u*)(p0B + plane);   vB1B = *(const f2u*)(p0B + plane + WW);
            vT2A = *(const f2u*)(p0A + 2*plane); vB2A = *(const f2u*)(p0A + 2*plane + WW);
            vT2B = *(const f2u*)(p0B + 2*plane); vB2B = *(const f2u*)(p0B + 2*plane + WW);
        } else {
            // pixel A guarded gather
            {
                const bool vy0 = (y0A >= 0)     & (y0A < HH);
                const bool vy1 = (y0A + 1 >= 0) & (y0A + 1 < HH);
                const bool vx0 = (x0A >= 0)     & (x0A < WW);
                const bool vx1 = (x0A + 1 >= 0) & (x0A + 1 < WW);
                const int yc0 = min(max(y0A, 0), HH - 1);
                const int yc1 = min(max(y0A + 1, 0), HH - 1);
                const int xc0 = min(max(x0A, 0), WW - 1);
                const int xc1 = min(max(x0A + 1, 0), WW - 1);
                const float* p0 = xb;
                const float* p1 = p0 + plane;
                const float* p2 = p1 + plane;
                vT0A.x = (vy0 & vx0) ? p0[yc0 * WW + xc0] : 0.0f;
                vT0A.y = (vy0 & vx1) ? p0[yc0 * WW + xc1] : 0.0f;
                vB0A.x = (vy1 & vx0) ? p0[yc1 * WW + xc0] : 0.0f;
                vB0A.y = (vy1 & vx1) ? p0[yc1 * WW + xc1] : 0.0f;
                vT1A.x = (vy0 & vx0) ? p1[yc0 * WW + xc0] : 0.0f;
                vT1A.y = (vy0 & vx1) ? p1[yc0 * WW + xc1] : 0.0f;
                vB1A.x = (vy1 & vx0) ? p1[yc1 * WW + xc0] : 0.0f;
                vB1A.y = (vy1 & vx1) ? p1[yc1 * WW + xc1] : 0.0f;
                vT2A.x = (vy0 & vx0) ? p2[yc0 * WW + xc0] : 0.0f;
                vT2A.y = (vy0 & vx1) ? p2[yc0 * WW + xc1] : 0.0f;
                vB2A.x = (vy1 & vx0) ? p2[yc1 * WW + xc0] : 0.0f;
                vB2A.y = (vy1 & vx1) ? p2[yc1 * WW + xc1] : 0.0f;
            }
            // pixel B guarded gather
            {
                const bool vy0 = (y0B >= 0)     & (y0B < HH);
                const bool vy1 = (y0B + 1 >= 0) & (y0B + 1 < HH);
                const bool vx0 = (x0B >= 0)     & (x0B < WW);
                const bool vx1 = (x0B + 1 >= 0) & (x0B + 1 < WW);
                const int yc0 = min(max(y0B, 0), HH - 1);
                const int yc1 = min(max(y0B + 1, 0), HH - 1);
                const int xc0 = min(max(x0B, 0), WW - 1);
                const int xc1 = min(max(x0B + 1, 0), WW - 1);
                const float* p0 = xb;
                const float* p1 = p0 + plane;
                const float* p2 = p1 + plane;
                vT0B.x = (vy0 & vx0) ? p0[yc0 * WW + xc0] : 0.0f;
                vT0B.y = (vy0 & vx1) ? p0[yc0 * WW + xc1] : 0.0f;
                vB0B.x = (vy1 & vx0) ? p0[yc1 * WW + xc0] : 0.0f;
                vB0B.y = (vy1 & vx1) ? p0[yc1 * WW + xc1] : 0.0f;
                vT1B.x = (vy0 & vx0) ? p1[yc0 * WW + xc0] : 0.0f;
                vT1B.y = (vy0 & vx1) ? p1[yc0 * WW + xc1] : 0.0f;
                vB1B.x = (vy1 & vx0) ? p1[yc1 * WW + xc0] : 0.0f;
                vB1B.y = (vy1 & vx1) ? p1[yc1 * WW + xc1] : 0.0f;
                vT2B.x = (vy0 & vx0) ? p2[yc0 * WW + xc0] : 0.0f;
                vT2B.y = (vy0 & vx1) ? p2[yc0 * WW + xc1] : 0.0f;
                vB2B.x = (vy1 & vx0) ? p2[yc1 * WW + xc0] : 0.0f;
                vB2B.y = (vy1 & vx1) ? p2[yc1 * WW + xc1] : 0.0f;
            }
        }

        // -- phase B: conv for tap k (independent of in-flight gathers) --
        if (k < KK) {
            CONV_TAP(k);
        }

        // -- phase C: consume tap kp's gathers --
        {
            f2 s0 = vT0A * wTA; s0 = __builtin_elementwise_fma(vB0A, wBA, s0);
            const float val0A = (s0.x + s0.y) * mA;
            f2 s1 = vT1A * wTA; s1 = __builtin_elementwise_fma(vB1A, wBA, s1);
            const float val1A = (s1.x + s1.y) * mA;
            f2 s2 = vT2A * wTA; s2 = __builtin_elementwise_fma(vB2A, wBA, s2);
            const float val2A = (s2.x + s2.y) * mA;

            f2 u0 = vT0B * wTB; u0 = __builtin_elementwise_fma(vB0B, wBB, u0);
            const float val0B = (u0.x + u0.y) * mB;
            f2 u1 = vT1B * wTB; u1 = __builtin_elementwise_fma(vB1B, wBB, u1);
            const float val1B = (u1.x + u1.y) * mB;
            f2 u2 = vT2B * wTB; u2 = __builtin_elementwise_fma(vB2B, wBB, u2);
            const float val2B = (u2.x + u2.y) * mB;

            const f2 w01_0 = { cw0.x, cw0.y };
            const f2 w01_1 = { cw1.x, cw1.y };
            const f2 w01_2 = { cw2.x, cw2.y };

            const f2 vv0A = { val0A, val0A };
            const f2 vv1A = { val1A, val1A };
            const f2 vv2A = { val2A, val2A };
            accA01 = __builtin_elementwise_fma(w01_0, vv0A, accA01);
            accA2 = fmaf(cw0.z, val0A, accA2);
            accA01 = __builtin_elementwise_fma(w01_1, vv1A, accA01);
            accA2 = fmaf(cw1.z, val1A, accA2);
            accA01 = __builtin_elementwise_fma(w01_2, vv2A, accA01);
            accA2 = fmaf(cw2.z, val2A, accA2);

            const f2 vv0B = { val0B, val0B };
            const f2 vv1B = { val1B, val1B };
            const f2 vv2B = { val2B, val2B };
            accB01 = __builtin_elementwise_fma(w01_0, vv0B, accB01);
            accB2 = fmaf(cw0.z, val0B, accB2);
            accB01 = __builtin_elementwise_fma(w01_1, vv1B, accB01);
            accB2 = fmaf(cw1.z, val1B, accB2);
            accB01 = __builtin_elementwise_fma(w01_2, vv2B, accB01);
            accB2 = fmaf(cw2.z, val2B, accB2);
        }
    }

    // ---- coalesced f2 stores: pixels (w0, w0+1) per output channel ----
    float* op = out + (size_t)b * (CIN * plane) + (size_t)h * WW + w0;
    *(f2u*)(op)             = (f2){ accA01.x, accB01.x };
    *(f2u*)(op + plane)     = (f2){ accA01.y, accB01.y };
    *(f2u*)(op + 2 * plane) = (f2){ accA2,    accB2    };
}

extern "C" void kernel_launch(void* const* d_in, const int* in_sizes, int n_in,
                              void* d_out, int out_size, void* d_ws, size_t ws_size,
                              hipStream_t stream) {
    const float* x     = (const float*)d_in[0];
    const float* w_off = (const float*)d_in[1];
    const float* b_off = (const float*)d_in[2];
    const float* w_def = (const float*)d_in[3];
    const float* b_def = (const float*)d_in[4];
    float* out = (float*)d_out;
    float* wsw = (float*)d_ws;   // 864 floats of reordered weights

    reorder_weights<<<1, 256, 0, stream>>>(w_off, w_def, wsw);

    dim3 block(256, 1, 1);
    dim3 grid(1, HH, BN);  // each block covers one full row (256 threads x 2 px)
    deform_fused_kernel<<<grid, block, 0, stream>>>(x, wsw, b_off, b_def, out);
}